// Round 8
// baseline (270.252 us; speedup 1.0000x reference)
//
#include <hip/hip_runtime.h>
#include <math.h>

#define NN 4096
#define ALPHA 0.1f
#define DT 0.01f
#define DIFF 10.0f
#define EPS 1e-9f
#define HB 1.5707963267948966f
#define CHUNK 2048               // steps per LDS fill (CHUNK * 32 B = 64 KB)

typedef float f32x4 __attribute__((ext_vector_type(4)));

#define SBAR __builtin_amdgcn_sched_barrier(0)
// Counted wait: with 7 pairs (14 reads) in flight, retire exactly the oldest
// pair (issued 6 steps ago). 14 <= 15 = lgkmcnt hardware cap (R6 peaked at 16
// -> issue-stall; that was the hidden serializer).
#define W12 do { asm volatile("s_waitcnt lgkmcnt(12)" ::: "memory"); SBAR; } while (0)
#define W0  do { asm volatile("s_waitcnt lgkmcnt(0)"  ::: "memory"); SBAR; } while (0)

// Two b128 reads of one step's constants into ext_vector regs (asm volatile:
// cannot be scalarized, sunk, or reordered among themselves). Proven in R6.
#define PRE1(DA, DB, av) do {                                              \
    asm volatile("ds_read_b128 %0, %1 offset:0"  : "=v"(DA) : "v"(av));    \
    asm volatile("ds_read_b128 %0, %1 offset:16" : "=v"(DB) : "v"(av));    \
  } while (0)

// One scan step, UNSCALED math (identical to R6, which passed at 1.2e-4):
//  q0=(ci,si,axx,ayy) q1=(xlo,xhi,ylo,yhi), bounds finite lo<hi -> med3==clamp
#define STEPQ(Q0, Q1, kk) do {                                 \
    float xd = fmaf((Q0).x, U, fmaf((Q0).y, V, (Q0).z));       \
    float yd = fmaf((Q0).y, U, fmaf(-(Q0).x, V, (Q0).w));      \
    float cx = __builtin_amdgcn_fmed3f(xd, (Q1).x, (Q1).y);    \
    float cy = __builtin_amdgcn_fmed3f(yd, (Q1).z, (Q1).w);    \
    float dx = cx * DT, dy = cy * DT;                          \
    U = fmaf((Q0).x, dx, fmaf((Q0).y, dy, U));                 \
    V = fmaf((Q0).y, dx, fmaf(-(Q0).x, dy, V));                \
    cyk = (lane == (kk)) ? cy : cyk;                           \
  } while (0)

__global__ __launch_bounds__(64, 1) void cpg_kernel(
    const float* __restrict__ phase, const float* __restrict__ amp,
    const float* __restrict__ w, const float* __restrict__ ha,
    const float* __restrict__ bvec, const float* __restrict__ xy,
    const float* __restrict__ xydo, float* __restrict__ out) {
  __shared__ f32x4 st[CHUNK * 2];   // 64 KB, refilled per chunk
  const int lane = threadIdx.x;
  const float2* xy2 = (const float2*)xy;
  const float2* xd2 = (const float2*)xydo;
  unsigned sbase = (unsigned)(uintptr_t)&st[0];   // LDS byte offset

  // ---- initial U = sum(cj*xj + sj*yj), V = sum(sj*xj - cj*yj) ----
  float u = 0.f, v = 0.f;
#pragma unroll 8
  for (int it = 0; it < NN / 64; ++it) {
    int i = it * 64 + lane;
    float s_, c_;
    sincosf(phase[i], &s_, &c_);
    float2 p = xy2[i];
    u = fmaf(c_, p.x, fmaf(s_, p.y, u));
    v = fmaf(s_, p.x, fmaf(-c_, p.y, v));
  }
#pragma unroll
  for (int off = 32; off; off >>= 1) {
    u += __shfl_xor(u, off, 64);
    v += __shfl_xor(v, off, 64);
  }
  float U = u, V = v;   // identical across lanes
  float cyk = 0.f;
  int tgt = lane;
  float ampC = amp[lane], bbC = bvec[lane], yiC = xy2[lane].y;

  for (int c = 0; c < NN / CHUNK; ++c) {
    __syncthreads();
    // ---- prep chunk c: fold per-step constants into LDS (R6-identical) ----
#pragma unroll 4
    for (int it2 = 0; it2 < CHUNK / 64; ++it2) {
      int s = it2 * 64 + lane;
      int i = c * CHUNK + s;
      float s_, c_;
      sincosf(phase[i], &s_, &c_);
      float2 p = xy2[i];
      float2 d = xd2[i];
      float r2 = fmaf(p.x, p.x, p.y * p.y);
      float ta = ALPHA * (1.f - r2 * r2);
      float zeta = 1.f - ha[i] * ((d.x + EPS) / (fabsf(d.x) + EPS));
      float tb = w[i] / (zeta + EPS);
      f32x4 q0 = {c_, s_, ta * p.x - tb * p.y - p.x, tb * p.x + ta * p.y - p.y};
      f32x4 q1 = {d.x - DIFF, d.x + DIFF, d.y - DIFF, d.y + DIFF};
      st[s * 2 + 0] = q0;
      st[s * 2 + 1] = q1;
    }
    __syncthreads();

    // ---- scan chunk: 8 single-step ring buffers, prefetch distance 6,
    //      peak 14 lgkm-ops in flight (cap-legal) ----
    f32x4 qa[8], qb[8];           // constant-indexed after unroll -> registers
    unsigned abase = sbase;       // byte base of current 64-step block
#pragma unroll
    for (int u0 = 0; u0 < 6; ++u0) {
      unsigned av = abase + (unsigned)(u0 * 32);
      PRE1(qa[u0], qb[u0], av);
    }
    for (int blk = 0; blk < CHUNK / 64; ++blk) {
#pragma unroll
      for (int uu = 0; uu < 64; ++uu) {
        // issue pair (blk*64 + uu + 6) into buf (uu+6)&7 -> 14 in flight
        unsigned av = abase + (unsigned)((uu + 6) * 32);
        PRE1(qa[(uu + 6) & 7], qb[(uu + 6) & 7], av);
        W12;  // retire pair uu (issued 6 steps / ~200 cyc ago)
        STEPQ(qa[uu & 7], qb[uu & 7], uu);
        // (tail prefetches cross into next block / past chunk end: never
        //  consumed before being rewritten; drained by W0 below)
      }
      // flush one 64-step block (coalesced, fused epilogue; vmcnt-only ops)
      float yn = fmaf(DT, cyk, yiC);
      float ang = fmaf(ampC, yn, bbC);
      out[tgt] = fminf(fmaxf(ang, -HB), HB);
      tgt += 64;
      int nb = (tgt < NN) ? tgt : (NN - 64 + lane);
      ampC = amp[nb]; bbC = bvec[nb]; yiC = xy2[nb].y;
      abase += 64 * 32;
    }
    W0;   // drain wrapped/OOB prefetches before LDS refill
  }
}

extern "C" void kernel_launch(void* const* d_in, const int* in_sizes, int n_in,
                              void* d_out, int out_size, void* d_ws, size_t ws_size,
                              hipStream_t stream) {
  const float* phase = (const float*)d_in[0];
  const float* amp   = (const float*)d_in[1];
  const float* w     = (const float*)d_in[2];
  const float* ha    = (const float*)d_in[3];
  const float* b     = (const float*)d_in[4];
  const float* xy    = (const float*)d_in[5];
  const float* xydo  = (const float*)d_in[6];
  float* out = (float*)d_out;

  cpg_kernel<<<1, 64, 0, stream>>>(phase, amp, w, ha, b, xy, xydo, out);
}

// Round 11
// 230.870 us; speedup vs baseline: 1.1706x; 1.1706x over previous
//
#include <hip/hip_runtime.h>
#include <math.h>

#define NN 4096
#define ALPHA 0.1f
#define DT 0.01f
#define DIFF 10.0f
#define EPS 1e-9f
#define HB 1.5707963267948966f

typedef float f32x2 __attribute__((ext_vector_type(2)));

#define SBAR __builtin_amdgcn_sched_barrier(0)
// Counted vm wait: retires the oldest block's 7 loads (over-waits by <=1 slot
// on interleaved stores, never under-waits; loads retire in order). One wait
// per 64 steps. SBAR stops VALU consumers hoisting above.
#define WV7  do { asm volatile("s_waitcnt vmcnt(7)" ::: "memory"); SBAR; } while (0)
#define WALL do { asm volatile("s_waitcnt vmcnt(0) lgkmcnt(0)" ::: "memory"); SBAR; } while (0)

__device__ __forceinline__ float rdlane(float v, int l) {
  return __int_as_float(__builtin_amdgcn_readlane(__float_as_int(v), l));
}

// Issue the 7 raw-input loads for one block (lane j -> element blk*64+j).
// asm volatile: cannot be scalarized/sunk/reordered vs the counted waits.
#define RAWLOAD(R, o1, o2) do {                                                     \
    unsigned _o1 = (o1), _o2 = (o2);                                                \
    asm volatile("global_load_dword %0, %1, %2"   : "=v"(R##_ph) : "v"(_o1), "s"(phase)); \
    asm volatile("global_load_dwordx2 %0, %1, %2" : "=v"(R##_xy) : "v"(_o2), "s"(xy));    \
    asm volatile("global_load_dwordx2 %0, %1, %2" : "=v"(R##_xd) : "v"(_o2), "s"(xydo));  \
    asm volatile("global_load_dword %0, %1, %2"   : "=v"(R##_ha) : "v"(_o1), "s"(ha));    \
    asm volatile("global_load_dword %0, %1, %2"   : "=v"(R##_w)  : "v"(_o1), "s"(w));     \
    asm volatile("global_load_dword %0, %1, %2"   : "=v"(R##_am) : "v"(_o1), "s"(amp));   \
    asm volatile("global_load_dword %0, %1, %2"   : "=v"(R##_bb) : "v"(_o1), "s"(bvec));  \
  } while (0)

// Fold raw inputs into this block's per-lane step constants.
// PRECISE sincosf (libm): native __cosf/__sinf (~2^-17) was R10's killer —
// the scan's ~1e3 error amplification blew it past threshold.
#define MKCONST(R)                                                       \
    float si, ci; sincosf(R##_ph, &si, &ci);                             \
    float xi = R##_xy.x, yi = R##_xy.y;                                  \
    float xdo = R##_xd.x, ydo = R##_xd.y;                                \
    float r2 = fmaf(xi, xi, yi * yi);                                    \
    float ta = ALPHA * (1.f - r2 * r2);                                  \
    float zeta = 1.f - R##_ha * ((xdo + EPS) / (fabsf(xdo) + EPS));      \
    float tb = R##_w / (zeta + EPS);                                     \
    float axx = ta * xi - tb * yi - xi;                                  \
    float ayy = tb * xi + ta * yi - yi;                                  \
    float xlo = xdo - DIFF, xhi = xdo + DIFF;                            \
    float ylo = ydo - DIFF, yhi = ydo + DIFF;                            \
    float cid = ci * DT, sid = si * DT;                                  \
    float ae = R##_am * DT;                                              \
    float be = fmaf(R##_am, yi, R##_bb);

// 64 serial steps + fused epilogue + coalesced store for one block.
#define BLOCKBODY(blk)                                                   \
    _Pragma("unroll")                                                    \
    for (int j = 0; j < 64; ++j) {                                       \
      float xd = fmaf(ci, U, fmaf(si, V, axx));                          \
      float yd = fmaf(si, U, fmaf(-ci, V, ayy));                         \
      float cx = __builtin_amdgcn_fmed3f(xd, xlo, xhi);                  \
      float cy = __builtin_amdgcn_fmed3f(yd, ylo, yhi);                  \
      float du = fmaf(sid, cy, cid * cx);                                \
      float dv = fmaf(-cid, cy, sid * cx);                               \
      U += rdlane(du, j);                                                \
      V += rdlane(dv, j);                                                \
      cyk = (lane == j) ? cy : cyk;                                      \
    }                                                                    \
    float ang = fmaf(ae, cyk, be);                                       \
    ang = fminf(fmaxf(ang, -HB), HB);                                    \
    {                                                                    \
      unsigned _so = (unsigned)(blk) * 256u + (unsigned)lane * 4u;       \
      asm volatile("global_store_dword %0, %1, %2"                       \
                   :: "v"(_so), "v"(ang), "s"(out) : "memory");          \
    }

__global__ __launch_bounds__(64, 1) void cpg_kernel(
    const float* __restrict__ phase, const float* __restrict__ amp,
    const float* __restrict__ w, const float* __restrict__ ha,
    const float* __restrict__ bvec, const float* __restrict__ xy,
    const float* __restrict__ xydo, float* __restrict__ out) {
  const int lane = threadIdx.x;
  const float2* xy2 = (const float2*)xy;

  // ---- initial U = sum(cj*xj + sj*yj), V = sum(sj*xj - cj*yj) ----
  // precise sincosf here too (R10 used __cosf/__sinf: ~1e-3 initial error).
  float u = 0.f, v = 0.f;
#pragma unroll 8
  for (int it = 0; it < NN / 64; ++it) {
    int i = it * 64 + lane;
    float s_, c_;
    sincosf(phase[i], &s_, &c_);
    float2 p = xy2[i];
    u = fmaf(c_, p.x, fmaf(s_, p.y, u));
    v = fmaf(s_, p.x, fmaf(-c_, p.y, v));
  }
#pragma unroll
  for (int off = 32; off; off >>= 1) {
    u += __shfl_xor(u, off, 64);
    v += __shfl_xor(v, off, 64);
  }
  float U = u, V = v;   // same value in all lanes
  float cyk = 0.f;
  WALL;                 // clean vm/lgkm state before counted pipeline

  // raw-input double buffers (block parity): 9 VGPRs each
  float RA_ph, RA_ha, RA_w, RA_am, RA_bb;  f32x2 RA_xy, RA_xd;
  float RB_ph, RB_ha, RB_w, RB_am, RB_bb;  f32x2 RB_xy, RB_xd;

  unsigned l4 = (unsigned)lane * 4u, l8 = (unsigned)lane * 8u;
  RAWLOAD(RA, l4, l8);                    // block 0
  RAWLOAD(RB, 256u + l4, 512u + l8);      // block 1

  for (int t = 0; t < 32; ++t) {
    int eb = 2 * t, ob = 2 * t + 1;
    {  // ---- even block: consume RA, prefetch block eb+2 into RA ----
      WV7;
      MKCONST(RA);
      int nb = (eb + 2 < 64) ? eb + 2 : 63;
      RAWLOAD(RA, (unsigned)nb * 256u + l4, (unsigned)nb * 512u + l8);
      BLOCKBODY(eb);
    }
    {  // ---- odd block: consume RB, prefetch block ob+2 into RB ----
      WV7;
      MKCONST(RB);
      int nb = (ob + 2 < 64) ? ob + 2 : 63;
      RAWLOAD(RB, (unsigned)nb * 256u + l4, (unsigned)nb * 512u + l8);
      BLOCKBODY(ob);
    }
  }
  WALL;   // drain clamped tail prefetches + stores
}

extern "C" void kernel_launch(void* const* d_in, const int* in_sizes, int n_in,
                              void* d_out, int out_size, void* d_ws, size_t ws_size,
                              hipStream_t stream) {
  const float* phase = (const float*)d_in[0];
  const float* amp   = (const float*)d_in[1];
  const float* w     = (const float*)d_in[2];
  const float* ha    = (const float*)d_in[3];
  const float* b     = (const float*)d_in[4];
  const float* xy    = (const float*)d_in[5];
  const float* xydo  = (const float*)d_in[6];
  float* out = (float*)d_out;

  cpg_kernel<<<1, 64, 0, stream>>>(phase, amp, w, ha, b, xy, xydo, out);
}

// Round 12
// 182.052 us; speedup vs baseline: 1.4845x; 1.2682x over previous
//
#include <hip/hip_runtime.h>
#include <math.h>

#define NN 4096
#define ALPHA 0.1f
#define DT 0.01f
#define DIFF 10.0f
#define EPS 1e-9f
#define HB 1.5707963267948966f

typedef float f32x2 __attribute__((ext_vector_type(2)));

#define SBAR __builtin_amdgcn_sched_barrier(0)
#define WV7  do { asm volatile("s_waitcnt vmcnt(7)" ::: "memory"); SBAR; } while (0)
#define WALL do { asm volatile("s_waitcnt vmcnt(0) lgkmcnt(0)" ::: "memory"); SBAR; } while (0)

__device__ __forceinline__ float rdlane(float v, int l) {
  return __int_as_float(__builtin_amdgcn_readlane(__float_as_int(v), l));
}

// Issue the 7 raw-input loads for one block (lane j -> element blk*64+j).
#define RAWLOAD(R, o1, o2) do {                                                     \
    unsigned _o1 = (o1), _o2 = (o2);                                                \
    asm volatile("global_load_dword %0, %1, %2"   : "=v"(R##_ph) : "v"(_o1), "s"(phase)); \
    asm volatile("global_load_dwordx2 %0, %1, %2" : "=v"(R##_xy) : "v"(_o2), "s"(xy));    \
    asm volatile("global_load_dwordx2 %0, %1, %2" : "=v"(R##_xd) : "v"(_o2), "s"(xydo));  \
    asm volatile("global_load_dword %0, %1, %2"   : "=v"(R##_ha) : "v"(_o1), "s"(ha));    \
    asm volatile("global_load_dword %0, %1, %2"   : "=v"(R##_w)  : "v"(_o1), "s"(w));     \
    asm volatile("global_load_dword %0, %1, %2"   : "=v"(R##_am) : "v"(_o1), "s"(amp));   \
    asm volatile("global_load_dword %0, %1, %2"   : "=v"(R##_bb) : "v"(_o1), "s"(bvec));  \
  } while (0)

// Fold raw inputs into this block's per-lane step constants (precise sincosf).
#define MKCONST(R)                                                       \
    float si, ci; sincosf(R##_ph, &si, &ci);                             \
    float xi = R##_xy.x, yi = R##_xy.y;                                  \
    float xdo = R##_xd.x, ydo = R##_xd.y;                                \
    float r2 = fmaf(xi, xi, yi * yi);                                    \
    float ta = ALPHA * (1.f - r2 * r2);                                  \
    float zeta = 1.f - R##_ha * ((xdo + EPS) / (fabsf(xdo) + EPS));      \
    float tb = R##_w / (zeta + EPS);                                     \
    float axx = ta * xi - tb * yi - xi;                                  \
    float ayy = tb * xi + ta * yi - yi;                                  \
    float xlo = xdo - DIFF, xhi = xdo + DIFF;                            \
    float ylo = ydo - DIFF, yhi = ydo + DIFF;                            \
    float cid = ci * DT, sid = si * DT;                                  \
    float ae = R##_am * DT;                                              \
    float be = fmaf(R##_am, yi, R##_bb);

// Exclusive wave-prefix of (du,dv): shift-by-1 then 6-stage inclusive scan.
#define PSCAN(eu, ev, du, dv) do {                                   \
    eu = __shfl_up(du, 1, 64); if (lane == 0) eu = 0.f;              \
    ev = __shfl_up(dv, 1, 64); if (lane == 0) ev = 0.f;              \
    _Pragma("unroll")                                                \
    for (int _o = 1; _o < 64; _o <<= 1) {                            \
      float _tu = __shfl_up(eu, _o, 64);                             \
      float _tv = __shfl_up(dv /*dummy*/ * 0.f + ev, _o, 64);        \
      eu += (lane >= _o) ? _tu : 0.f;                                \
      ev += (lane >= _o) ? _tv : 0.f;                                \
    }                                                                \
  } while (0)

// Jacobi fixed-point block solve: lane j owns step blk*64+j.
// Lower-triangular dependency => lane j's d provably fixed after <= j+1
// sweeps => cap 64 is exact; ballot exits early (typ. 3-4 sweeps since
// ~87% of steps are clip-saturated -> d independent of U,V).
#define BLOCKBODY(blk)                                               \
    {                                                                \
      float du = 0.f, dv = 0.f, cyv = 0.f, exu = 0.f, exv = 0.f;     \
      _Pragma("unroll 1")                                            \
      for (int k = 0; k < 64; ++k) {                                 \
        float eu, ev;                                                \
        if (k) { PSCAN(eu, ev, du, dv); } else { eu = 0.f; ev = 0.f; } \
        float Uj = U + eu, Vj = V + ev;                              \
        float xd = fmaf(ci, Uj, fmaf(si, Vj, axx));                  \
        float yd = fmaf(si, Uj, fmaf(-ci, Vj, ayy));                 \
        float cx = __builtin_amdgcn_fmed3f(xd, xlo, xhi);            \
        float cy = __builtin_amdgcn_fmed3f(yd, ylo, yhi);            \
        float du2 = fmaf(sid, cy, cid * cx);                         \
        float dv2 = fmaf(-cid, cy, sid * cx);                        \
        unsigned long long chg =                                     \
            __ballot(du2 != du || dv2 != dv || cy != cyv);           \
        du = du2; dv = dv2; cyv = cy; exu = eu; exv = ev;            \
        if (chg == 0ull) break;                                      \
      }                                                              \
      float tu = exu + du, tv = exv + dv;                            \
      U += rdlane(tu, 63);                                           \
      V += rdlane(tv, 63);                                           \
      float ang = fmaf(ae, cyv, be);                                 \
      ang = fminf(fmaxf(ang, -HB), HB);                              \
      unsigned _so = (unsigned)(blk) * 256u + (unsigned)lane * 4u;   \
      asm volatile("global_store_dword %0, %1, %2"                   \
                   :: "v"(_so), "v"(ang), "s"(out) : "memory");      \
    }

__global__ __launch_bounds__(64, 1) void cpg_kernel(
    const float* __restrict__ phase, const float* __restrict__ amp,
    const float* __restrict__ w, const float* __restrict__ ha,
    const float* __restrict__ bvec, const float* __restrict__ xy,
    const float* __restrict__ xydo, float* __restrict__ out) {
  const int lane = threadIdx.x;
  const float2* xy2 = (const float2*)xy;

  // ---- initial U = sum(cj*xj + sj*yj), V = sum(sj*xj - cj*yj) ----
  float u = 0.f, v = 0.f;
#pragma unroll 8
  for (int it = 0; it < NN / 64; ++it) {
    int i = it * 64 + lane;
    float s_, c_;
    sincosf(phase[i], &s_, &c_);
    float2 p = xy2[i];
    u = fmaf(c_, p.x, fmaf(s_, p.y, u));
    v = fmaf(s_, p.x, fmaf(-c_, p.y, v));
  }
#pragma unroll
  for (int off = 32; off; off >>= 1) {
    u += __shfl_xor(u, off, 64);
    v += __shfl_xor(v, off, 64);
  }
  float U = u, V = v;   // wave-uniform
  WALL;

  // raw-input double buffers (block parity): 9 VGPRs each
  float RA_ph, RA_ha, RA_w, RA_am, RA_bb;  f32x2 RA_xy, RA_xd;
  float RB_ph, RB_ha, RB_w, RB_am, RB_bb;  f32x2 RB_xy, RB_xd;

  unsigned l4 = (unsigned)lane * 4u, l8 = (unsigned)lane * 8u;
  RAWLOAD(RA, l4, l8);                    // block 0
  RAWLOAD(RB, 256u + l4, 512u + l8);      // block 1

  for (int t = 0; t < 32; ++t) {
    int eb = 2 * t, ob = 2 * t + 1;
    {  // ---- even block: consume RA, prefetch eb+2 into RA ----
      WV7;
      MKCONST(RA);
      int nb = (eb + 2 < 64) ? eb + 2 : 63;
      RAWLOAD(RA, (unsigned)nb * 256u + l4, (unsigned)nb * 512u + l8);
      BLOCKBODY(eb);
    }
    {  // ---- odd block: consume RB, prefetch ob+2 into RB ----
      WV7;
      MKCONST(RB);
      int nb = (ob + 2 < 64) ? ob + 2 : 63;
      RAWLOAD(RB, (unsigned)nb * 256u + l4, (unsigned)nb * 512u + l8);
      BLOCKBODY(ob);
    }
  }
  WALL;   // drain tail prefetches + stores
}

extern "C" void kernel_launch(void* const* d_in, const int* in_sizes, int n_in,
                              void* d_out, int out_size, void* d_ws, size_t ws_size,
                              hipStream_t stream) {
  const float* phase = (const float*)d_in[0];
  const float* amp   = (const float*)d_in[1];
  const float* w     = (const float*)d_in[2];
  const float* ha    = (const float*)d_in[3];
  const float* b     = (const float*)d_in[4];
  const float* xy    = (const float*)d_in[5];
  const float* xydo  = (const float*)d_in[6];
  float* out = (float*)d_out;

  cpg_kernel<<<1, 64, 0, stream>>>(phase, amp, w, ha, b, xy, xydo, out);
}

// Round 13
// 94.377 us; speedup vs baseline: 2.8635x; 1.9290x over previous
//
#include <hip/hip_runtime.h>
#include <math.h>

#define NN 4096
#define TPB 512
#define SPT 8               // steps per thread
#define NW (TPB / 64)       // 8 waves
#define ALPHA 0.1f
#define DT 0.01f
#define DIFF 10.0f
#define EPS 1e-9f
#define HB 1.5707963267948966f
#define MAXS 520            // > 513 = provable bitwise-exact cap (triangular dep)

__global__ __launch_bounds__(TPB, 2) void cpg_kernel(
    const float* __restrict__ phase, const float* __restrict__ amp,
    const float* __restrict__ w, const float* __restrict__ ha,
    const float* __restrict__ bvec, const float* __restrict__ xy,
    const float* __restrict__ xydo, float* __restrict__ out) {
  __shared__ alignas(16) float totU[8];
  __shared__ alignas(16) float totV[8];
  __shared__ float redU[NW], redV[NW];
  __shared__ float aeS[NN], beS[NN];   // 32 KB epilogue constants
  const int tid = threadIdx.x;
  const int lane = tid & 63;
  const int wid = tid >> 6;
  const int g0 = tid * SPT;

  // ---- prep: per-thread constants for its 8 contiguous steps ----
  float ci[SPT], si[SPT], axx[SPT], ayy[SPT];
  float xlo[SPT], xhi[SPT], ylo[SPT], yhi[SPT];
  float u0 = 0.f, v0 = 0.f;
#pragma unroll
  for (int k = 0; k < SPT; ++k) {
    int i = g0 + k;
    float s_, c_;
    sincosf(phase[i], &s_, &c_);       // precise (native sin/cos failed R10)
    float2 p = ((const float2*)xy)[i];
    float2 d = ((const float2*)xydo)[i];
    float r2 = fmaf(p.x, p.x, p.y * p.y);
    float ta = ALPHA * (1.f - r2 * r2);
    float zeta = 1.f - ha[i] * ((d.x + EPS) / (fabsf(d.x) + EPS));
    float tb = w[i] / (zeta + EPS);
    ci[k] = c_; si[k] = s_;
    axx[k] = ta * p.x - tb * p.y - p.x;
    ayy[k] = tb * p.x + ta * p.y - p.y;
    xlo[k] = d.x - DIFF; xhi[k] = d.x + DIFF;
    ylo[k] = d.y - DIFF; yhi[k] = d.y + DIFF;
    float am = amp[i];
    aeS[i] = am * DT;                   // out = clamp(ae*cy + be)
    beS[i] = fmaf(am, p.y, bvec[i]);
    u0 = fmaf(c_, p.x, fmaf(s_, p.y, u0));
    v0 = fmaf(s_, p.x, fmaf(-c_, p.y, v0));
  }
  // ---- block reduce for initial U0,V0 (deterministic order) ----
#pragma unroll
  for (int off = 32; off; off >>= 1) {
    u0 += __shfl_xor(u0, off, 64);
    v0 += __shfl_xor(v0, off, 64);
  }
  if (lane == 0) { redU[wid] = u0; redV[wid] = v0; }
  __syncthreads();
  float U0 = 0.f, V0 = 0.f;
#pragma unroll
  for (int ww = 0; ww < NW; ++ww) { U0 += redU[ww]; V0 += redV[ww]; }

  // ---- global Jacobi fixed point ----
  float su = 0.f, sv = 0.f;
  float cy[SPT];
#pragma unroll
  for (int k = 0; k < SPT; ++k) cy[k] = 0.f;

#pragma unroll 1
  for (int s = 0; s < MAXS; ++s) {
    // exclusive wave-level prefix of (su,sv)  (R12-proven scan)
    float eu = __shfl_up(su, 1, 64); if (lane == 0) eu = 0.f;
    float ev = __shfl_up(sv, 1, 64); if (lane == 0) ev = 0.f;
#pragma unroll
    for (int o = 1; o < 64; o <<= 1) {
      float tu = __shfl_up(eu, o, 64);
      float tv = __shfl_up(ev, o, 64);
      eu += (lane >= o) ? tu : 0.f;
      ev += (lane >= o) ? tv : 0.f;
    }
    if (lane == 63) { totU[wid] = eu + su; totV[wid] = ev + sv; }  // wave totals
    __syncthreads();
    float4 tU0 = *((const float4*)totU), tU1 = *(((const float4*)totU) + 1);
    float4 tV0 = *((const float4*)totV), tV1 = *(((const float4*)totV) + 1);
    float cu = 0.f, cv = 0.f;
    if (wid > 0) { cu += tU0.x; cv += tV0.x; }
    if (wid > 1) { cu += tU0.y; cv += tV0.y; }
    if (wid > 2) { cu += tU0.z; cv += tV0.z; }
    if (wid > 3) { cu += tU0.w; cv += tV0.w; }
    if (wid > 4) { cu += tU1.x; cv += tV1.x; }
    if (wid > 5) { cu += tU1.y; cv += tV1.y; }
    if (wid > 6) { cu += tU1.z; cv += tV1.z; }
    (void)tU1.w; (void)tV1.w;

    float base_u = U0 + cu + eu;     // U at this thread's segment start
    float base_v = V0 + cv + ev;
    float nsu = 0.f, nsv = 0.f;
    bool chg = false;
#pragma unroll
    for (int k = 0; k < SPT; ++k) {  // exact serial inside segment
      float Uc = base_u + nsu, Vc = base_v + nsv;
      float xd = fmaf(ci[k], Uc, fmaf(si[k], Vc, axx[k]));
      float yd = fmaf(si[k], Uc, fmaf(-ci[k], Vc, ayy[k]));
      float cx = __builtin_amdgcn_fmed3f(xd, xlo[k], xhi[k]);
      float cyk = __builtin_amdgcn_fmed3f(yd, ylo[k], yhi[k]);
      float dx = cx * DT, dy = cyk * DT;
      nsu = fmaf(ci[k], dx, fmaf(si[k], dy, nsu));
      nsv = fmaf(si[k], dx, fmaf(-ci[k], dy, nsv));
      chg = chg || (cyk != cy[k]);
      cy[k] = cyk;
    }
    chg = chg || (nsu != su) || (nsv != sv);
    su = nsu; sv = nsv;
    if (__syncthreads_count((int)chg) == 0) break;  // all bitwise stable
  }

  // ---- epilogue: coalesced float4 stores ----
  float res[SPT];
#pragma unroll
  for (int k = 0; k < SPT; ++k) {
    float ang = fmaf(aeS[g0 + k], cy[k], beS[g0 + k]);
    res[k] = fminf(fmaxf(ang, -HB), HB);
  }
  ((float4*)out)[tid * 2 + 0] = make_float4(res[0], res[1], res[2], res[3]);
  ((float4*)out)[tid * 2 + 1] = make_float4(res[4], res[5], res[6], res[7]);
}

extern "C" void kernel_launch(void* const* d_in, const int* in_sizes, int n_in,
                              void* d_out, int out_size, void* d_ws, size_t ws_size,
                              hipStream_t stream) {
  const float* phase = (const float*)d_in[0];
  const float* amp   = (const float*)d_in[1];
  const float* w     = (const float*)d_in[2];
  const float* ha    = (const float*)d_in[3];
  const float* b     = (const float*)d_in[4];
  const float* xy    = (const float*)d_in[5];
  const float* xydo  = (const float*)d_in[6];
  float* out = (float*)d_out;

  cpg_kernel<<<1, TPB, 0, stream>>>(phase, amp, w, ha, b, xy, xydo, out);
}